// Round 1
// baseline (810.458 us; speedup 1.0000x reference)
//
#include <hip/hip_runtime.h>

typedef unsigned short u16;
typedef __attribute__((ext_vector_type(8))) unsigned short u16x8;
typedef __attribute__((ext_vector_type(4))) unsigned short u16x4;
typedef __attribute__((ext_vector_type(4))) float f32x4;

#define DEVI __device__ __forceinline__

// ---------------- helpers ----------------
DEVI u16 f2bf(float f){
  unsigned u = __float_as_uint(f);
  u += 0x7FFFu + ((u >> 16) & 1u);      // round-to-nearest-even
  return (u16)(u >> 16);
}

DEVI void gload16(const void* g, void* l){
  __builtin_amdgcn_global_load_lds((const __attribute__((address_space(1))) void*)g,
                                   (__attribute__((address_space(3))) void*)l, 16, 0, 0);
}

DEVI float wave_sum(float v){
#pragma unroll
  for (int o = 32; o; o >>= 1) v += __shfl_xor(v, o, 64);
  return v;
}
DEVI float wave_max(float v){
#pragma unroll
  for (int o = 32; o; o >>= 1) v = fmaxf(v, __shfl_xor(v, o, 64));
  return v;
}

#define MFMA16(a,b,c) __builtin_amdgcn_mfma_f32_16x16x32_bf16((a),(b),(c),0,0,0)

// ---------------- elementwise convert f32 -> bf16 ----------------
__global__ __launch_bounds__(256) void f32_to_bf16_k(const float* __restrict__ in,
                                                     u16* __restrict__ out, int n4){
  int i = blockIdx.x * 256 + threadIdx.x;
  if (i < n4){
    float4 v = ((const float4*)in)[i];
    u16x4 o = { f2bf(v.x), f2bf(v.y), f2bf(v.z), f2bf(v.w) };
    ((u16x4*)out)[i] = o;
  }
}

// ---------------- transpose f32 [R][C] -> bf16 [C][R] ----------------
__global__ __launch_bounds__(256) void trans_f32_bf16_k(const float* __restrict__ in,
                                                        u16* __restrict__ out, int R, int C){
  __shared__ u16 tile[32][33];
  const int c0 = blockIdx.x * 32, r0 = blockIdx.y * 32;
  const int tx = threadIdx.x & 31, ty = threadIdx.x >> 5;
#pragma unroll
  for (int k = 0; k < 4; k++)
    tile[ty + k*8][tx] = f2bf(in[(size_t)(r0 + ty + k*8) * C + c0 + tx]);
  __syncthreads();
#pragma unroll
  for (int k = 0; k < 4; k++)
    out[(size_t)(c0 + ty + k*8) * R + r0 + tx] = tile[tx][ty + k*8];
}

// ---------------- V transpose: bf16 [B*T][N*H] -> [B][N][H][T] ----------------
__global__ __launch_bounds__(256) void vtrans_k(const u16* __restrict__ V, u16* __restrict__ Vt){
  __shared__ u16 tile[32][33];
  const int t0 = blockIdx.x * 32;
  const int h0 = blockIdx.y * 32;
  const int bn = blockIdx.z; const int b = bn >> 4, n = bn & 15;
  const int tx = threadIdx.x & 31, ty = threadIdx.x >> 5;
#pragma unroll
  for (int k = 0; k < 4; k++)
    tile[ty + k*8][tx] = V[(size_t)(b*512 + t0 + ty + k*8) * 1024 + n*64 + h0 + tx];
  __syncthreads();
#pragma unroll
  for (int k = 0; k < 4; k++)
    Vt[(size_t)((b*16 + n)*64 + h0 + ty + k*8) * 512 + t0 + tx] = tile[tx][ty + k*8];
}

// ---------------- layernorm: rows of 1024, (x-m)/(std+eps) ----------------
template<int OUTF32>
__global__ __launch_bounds__(256) void layernorm_k(const float* __restrict__ in, void* __restrict__ outp){
  const int row = blockIdx.x;
  const int tid = threadIdx.x;
  const float4 v = ((const float4*)(in + (size_t)row * 1024))[tid];
  __shared__ float sb[8];
  const int wid = tid >> 6, lane = tid & 63;
  float s = wave_sum(v.x + v.y + v.z + v.w);
  if (lane == 0) sb[wid] = s;
  __syncthreads();
  const float mean = (sb[0] + sb[1] + sb[2] + sb[3]) * (1.0f / 1024.0f);
  const float dx = v.x - mean, dy = v.y - mean, dz = v.z - mean, dw = v.w - mean;
  float q = wave_sum(dx*dx + dy*dy + dz*dz + dw*dw);
  if (lane == 0) sb[4 + wid] = q;
  __syncthreads();
  const float sd = sqrtf((sb[4] + sb[5] + sb[6] + sb[7]) * (1.0f / 1024.0f));
  const float inv = 1.0f / (sd + 1e-6f);
  if (OUTF32){
    ((float4*)outp)[(size_t)row * 256 + tid] = make_float4(dx*inv, dy*inv, dz*inv, dw*inv);
  } else {
    u16x4 o = { f2bf(dx*inv), f2bf(dy*inv), f2bf(dz*inv), f2bf(dw*inv) };
    ((u16x4*)outp)[(size_t)row * 256 + tid] = o;
  }
}

// ---------------- time-bias MLP: qs[b,f,t] ----------------
__global__ __launch_bounds__(256) void qsbias_k(const float* __restrict__ dist,
    const float* __restrict__ Wth, const float* __restrict__ bth,
    const float* __restrict__ Wto, const float* __restrict__ bto,
    float* __restrict__ qs){
  const int idx = blockIdx.x * 256 + threadIdx.x;        // over B*F*T/4
  float4 s4 = ((const float4*)dist)[idx];
  float sv[4] = { s4.x, s4.y, s4.z, s4.w };
  float r[4];
  const float b0 = bto[0];
#pragma unroll
  for (int c = 0; c < 4; c++) r[c] = b0;
#pragma unroll
  for (int k = 0; k < 32; k++){
    const float wk = Wth[k], bk = bth[k], ok = Wto[k];
#pragma unroll
    for (int c = 0; c < 4; c++){
      float h = fmaxf(sv[c] * wk + bk, 0.0f);
      r[c] += h * ok;
    }
  }
  ((float4*)qs)[idx] = make_float4(r[0], r[1], r[2], r[3]);
}

// ---------------- main GEMM: C[M][Nd] = A[M][Kd] @ Bt[Nd][Kd]^T ----------------
// MODE 0: bf16 out   1: bf16 out * scale   2: f32 out + resid
// MODE 3: bf16 relu(out + bias)            4: f32 out + bias + resid
template<int MODE, int BM, int BN>
__global__ __launch_bounds__(256) void gemm_k(const u16* __restrict__ A, const u16* __restrict__ Bt,
    const int Kd, const int Nd, void* __restrict__ Cout,
    const float* __restrict__ bias, const float* __restrict__ resid, const float scale){
  constexpr int WM = BM/2, WN = BN/2, FM = WM/16, FN = WN/16;
  __shared__ __align__(16) u16 Als[BM * 64];
  __shared__ __align__(16) u16 Bls[BN * 64];
  const int tid = threadIdx.x;
  const int wid = tid >> 6, lane = tid & 63;
  const int wm = wid >> 1, wn = wid & 1;
  const int row0 = blockIdx.y * BM, col0 = blockIdx.x * BN;
  const int lrow = lane & 15, lk = (lane >> 4) * 8;
  f32x4 acc[FM][FN] = {};

  const u16* Ag = A + (size_t)(row0 + wid*(BM/4) + (lane >> 3)) * Kd + (lane & 7) * 8;
  const u16* Bg = Bt + (size_t)(col0 + wid*(BN/4) + (lane >> 3)) * Kd + (lane & 7) * 8;
  u16* AlsW = Als + wid * (BM/4) * 64;
  u16* BlsW = Bls + wid * (BN/4) * 64;

  for (int k0 = 0; k0 < Kd; k0 += 64){
#pragma unroll
    for (int q = 0; q < BM/32; q++) gload16(Ag + (size_t)q*8*Kd + k0, AlsW + q*8*64);
#pragma unroll
    for (int q = 0; q < BN/32; q++) gload16(Bg + (size_t)q*8*Kd + k0, BlsW + q*8*64);
    __syncthreads();    // compiler drains vmcnt before barrier
#pragma unroll
    for (int ks = 0; ks < 2; ks++){
      u16x8 av[FM], bv[FN];
#pragma unroll
      for (int mi = 0; mi < FM; mi++)
        av[mi] = *(const u16x8*)(Als + (wm*WM + mi*16 + lrow) * 64 + ks*32 + lk);
#pragma unroll
      for (int ni = 0; ni < FN; ni++)
        bv[ni] = *(const u16x8*)(Bls + (wn*WN + ni*16 + lrow) * 64 + ks*32 + lk);
#pragma unroll
      for (int mi = 0; mi < FM; mi++)
#pragma unroll
        for (int ni = 0; ni < FN; ni++)
          acc[mi][ni] = MFMA16(av[mi], bv[ni], acc[mi][ni]);
    }
    __syncthreads();
  }

#pragma unroll
  for (int mi = 0; mi < FM; mi++){
#pragma unroll
    for (int ni = 0; ni < FN; ni++){
      const int col = col0 + wn*WN + ni*16 + lrow;
#pragma unroll
      for (int j = 0; j < 4; j++){
        const int row = row0 + wm*WM + mi*16 + (lane >> 4)*4 + j;
        float v = acc[mi][ni][j];
        if (MODE == 1) v *= scale;
        if (MODE == 3) v = fmaxf(v + bias[col], 0.0f);
        if (MODE == 4) v = v + bias[col] + resid[(size_t)row * Nd + col];
        if (MODE == 2) v = v + resid[(size_t)row * Nd + col];
        if (MODE == 0 || MODE == 1 || MODE == 3)
          ((u16*)Cout)[(size_t)row * Nd + col] = f2bf(v);
        else
          ((float*)Cout)[(size_t)row * Nd + col] = v;
      }
    }
  }
}

// ---------------- logits: per (b,n) 64x64 tile of Q @ K^T + biases ----------------
__global__ __launch_bounds__(256) void logits_k(const u16* __restrict__ Q, const u16* __restrict__ Kp,
    const float* __restrict__ qs, const float* __restrict__ abias, float* __restrict__ lg){
  const int bn = blockIdx.z, b = bn >> 4, n = bn & 15;
  const int f0 = blockIdx.x * 64, t0 = blockIdx.y * 64;
  const int wid = threadIdx.x >> 6, lane = threadIdx.x & 63;
  const int wm = wid >> 1, wn = wid & 1;
  const int lrow = lane & 15, lk = (lane >> 4) * 8;
  const u16* qb = Q + (size_t)b * 512 * 1024 + n * 64;
  const u16* kb = Kp + (size_t)b * 512 * 1024 + n * 64;
  f32x4 acc[2][2] = {};
#pragma unroll
  for (int ks = 0; ks < 2; ks++){
    u16x8 av[2], bv[2];
#pragma unroll
    for (int mi = 0; mi < 2; mi++)
      av[mi] = *(const u16x8*)(qb + (size_t)(f0 + wm*32 + mi*16 + lrow) * 1024 + ks*32 + lk);
#pragma unroll
    for (int ni = 0; ni < 2; ni++)
      bv[ni] = *(const u16x8*)(kb + (size_t)(t0 + wn*32 + ni*16 + lrow) * 1024 + ks*32 + lk);
#pragma unroll
    for (int mi = 0; mi < 2; mi++)
#pragma unroll
      for (int ni = 0; ni < 2; ni++)
        acc[mi][ni] = MFMA16(av[mi], bv[ni], acc[mi][ni]);
  }
  float* lout = lg + (size_t)(b*16 + n) * 512 * 512;
#pragma unroll
  for (int mi = 0; mi < 2; mi++)
#pragma unroll
    for (int ni = 0; ni < 2; ni++){
      const int t = t0 + wn*32 + ni*16 + lrow;
#pragma unroll
      for (int j = 0; j < 4; j++){
        const int f = f0 + wm*32 + mi*16 + (lane >> 4)*4 + j;
        lout[(size_t)f * 512 + t] = acc[mi][ni][j] + abias[b*512 + t]
                                  + qs[((size_t)b*512 + f) * 512 + t];
      }
    }
}

// ---------------- softmax over 512 (one wave per row), write bf16 ----------------
__global__ __launch_bounds__(256) void softmax_k(const float* __restrict__ lg, u16* __restrict__ wsm){
  const int row = blockIdx.x * 4 + (threadIdx.x >> 6);
  const int lane = threadIdx.x & 63;
  const float4* lp = (const float4*)(lg + (size_t)row * 512 + lane * 8);
  float4 a = lp[0], c = lp[1];
  float v[8] = { a.x, a.y, a.z, a.w, c.x, c.y, c.z, c.w };
  float mx = v[0];
#pragma unroll
  for (int k = 1; k < 8; k++) mx = fmaxf(mx, v[k]);
  mx = wave_max(mx);
  float sum = 0.0f;
#pragma unroll
  for (int k = 0; k < 8; k++){ v[k] = __expf(v[k] - mx); sum += v[k]; }
  sum = wave_sum(sum);
  const float inv = 1.0f / sum;
  union { u16x8 v8; u16 e[8]; } o;
#pragma unroll
  for (int k = 0; k < 8; k++) o.e[k] = f2bf(v[k] * inv);
  *(u16x8*)(wsm + (size_t)row * 512 + lane * 8) = o.v8;
}

// ---------------- PV: per (b,n): [512,512] @ V -> [512,64], bf16 out ----------------
__global__ __launch_bounds__(256) void pv_k(const u16* __restrict__ P, const u16* __restrict__ Vt,
                                            u16* __restrict__ aout){
  const int bn = blockIdx.y, b = bn >> 4, n = bn & 15;
  const int f0 = blockIdx.x * 64;
  const int wid = threadIdx.x >> 6, lane = threadIdx.x & 63;
  const int wm = wid >> 1, wn = wid & 1;
  const int lrow = lane & 15, lk = (lane >> 4) * 8;
  const u16* pb = P + (size_t)(b*16 + n) * 512 * 512;
  const u16* vb = Vt + (size_t)(b*16 + n) * 64 * 512;
  f32x4 acc[2][2] = {};
  for (int kk = 0; kk < 16; kk++){
    u16x8 av[2], bv[2];
#pragma unroll
    for (int mi = 0; mi < 2; mi++)
      av[mi] = *(const u16x8*)(pb + (size_t)(f0 + wm*32 + mi*16 + lrow) * 512 + kk*32 + lk);
#pragma unroll
    for (int ni = 0; ni < 2; ni++)
      bv[ni] = *(const u16x8*)(vb + (size_t)(wn*32 + ni*16 + lrow) * 512 + kk*32 + lk);
#pragma unroll
    for (int mi = 0; mi < 2; mi++)
#pragma unroll
      for (int ni = 0; ni < 2; ni++)
        acc[mi][ni] = MFMA16(av[mi], bv[ni], acc[mi][ni]);
  }
#pragma unroll
  for (int mi = 0; mi < 2; mi++)
#pragma unroll
    for (int ni = 0; ni < 2; ni++){
      const int h = wn*32 + ni*16 + lrow;
#pragma unroll
      for (int j = 0; j < 4; j++){
        const int f = f0 + wm*32 + mi*16 + (lane >> 4)*4 + j;
        aout[(size_t)(b*512 + f) * 1024 + n*64 + h] = f2bf(acc[mi][ni][j]);
      }
    }
}

// ---------------- host ----------------
extern "C" void kernel_launch(void* const* d_in, const int* in_sizes, int n_in,
                              void* d_out, int out_size, void* d_ws, size_t ws_size,
                              hipStream_t stream){
  const float* dec_in   = (const float*)d_in[0];
  const float* enc      = (const float*)d_in[1];
  const float* dist     = (const float*)d_in[3];
  const float* abias    = (const float*)d_in[5];
  const float* Wq  = (const float*)d_in[6];
  const float* Wk  = (const float*)d_in[7];
  const float* Wv  = (const float*)d_in[8];
  const float* Wo  = (const float*)d_in[9];
  const float* Wth = (const float*)d_in[10];
  const float* bth = (const float*)d_in[11];
  const float* Wto = (const float*)d_in[12];
  const float* bto = (const float*)d_in[13];
  const float* Wf1 = (const float*)d_in[14];
  const float* bf1 = (const float*)d_in[15];
  const float* Wf2 = (const float*)d_in[16];
  const float* bf2 = (const float*)d_in[17];
  float* dout = (float*)d_out;

  char* wp = (char*)d_ws;
  auto alloc = [&](size_t n) -> char* {
    char* p = wp; wp += (n + 255) & ~(size_t)255; return p;
  };
  float* x    = (float*)alloc((size_t)1048576 * 4);
  u16*  xn    = (u16*)alloc((size_t)1048576 * 2);
  u16*  encb  = (u16*)alloc((size_t)1048576 * 2);
  u16*  Wqt   = (u16*)alloc((size_t)1048576 * 2);
  u16*  Wkt   = (u16*)alloc((size_t)1048576 * 2);
  u16*  Wvt   = (u16*)alloc((size_t)1048576 * 2);
  u16*  Wot   = (u16*)alloc((size_t)1048576 * 2);
  u16*  Wf1t  = (u16*)alloc((size_t)4194304 * 2);
  u16*  Wf2t  = (u16*)alloc((size_t)4194304 * 2);
  u16*  Kb    = (u16*)alloc((size_t)1048576 * 2);
  u16*  Vb    = (u16*)alloc((size_t)1048576 * 2);
  u16*  Vt    = (u16*)alloc((size_t)1048576 * 2);
  u16*  Qb    = (u16*)alloc((size_t)1048576 * 2);
  float* qs   = (float*)alloc((size_t)524288 * 4);
  float* lg   = (float*)alloc((size_t)8388608 * 4);
  u16*  wsm   = (u16*)alloc((size_t)8388608 * 2);
  u16*  aout  = (u16*)alloc((size_t)1048576 * 2);
  u16*  ffh   = (u16*)alloc((size_t)4194304 * 2);

  hipMemcpyAsync(x, dec_in, (size_t)1048576 * 4, hipMemcpyDeviceToDevice, stream);
  f32_to_bf16_k<<<1024, 256, 0, stream>>>(enc, encb, 262144);

  for (int i = 0; i < 4; i++){
    // weight convert + transpose (f32 [K][N] -> bf16 [N][K])
    trans_f32_bf16_k<<<dim3(32, 32), 256, 0, stream>>>(Wq + (size_t)i*1048576, Wqt, 1024, 1024);
    trans_f32_bf16_k<<<dim3(32, 32), 256, 0, stream>>>(Wk + (size_t)i*1048576, Wkt, 1024, 1024);
    trans_f32_bf16_k<<<dim3(32, 32), 256, 0, stream>>>(Wv + (size_t)i*1048576, Wvt, 1024, 1024);
    trans_f32_bf16_k<<<dim3(32, 32), 256, 0, stream>>>(Wo + (size_t)i*1048576, Wot, 1024, 1024);
    trans_f32_bf16_k<<<dim3(128, 32), 256, 0, stream>>>(Wf1 + (size_t)i*4194304, Wf1t, 1024, 4096);
    trans_f32_bf16_k<<<dim3(32, 128), 256, 0, stream>>>(Wf2 + (size_t)i*4194304, Wf2t, 4096, 1024);

    qsbias_k<<<512, 256, 0, stream>>>(dist, Wth + i*32, bth + i*32, Wto + i*32, bto + i, qs);

    // K,V projections from raw encoder outputs
    gemm_k<0,64,64><<<dim3(16,16), 256, 0, stream>>>(encb, Wkt, 1024, 1024, Kb, nullptr, nullptr, 1.0f);
    gemm_k<0,64,64><<<dim3(16,16), 256, 0, stream>>>(encb, Wvt, 1024, 1024, Vb, nullptr, nullptr, 1.0f);
    vtrans_k<<<dim3(16, 2, 32), 256, 0, stream>>>(Vb, Vt);

    // pre-norm -> Q
    layernorm_k<0><<<1024, 256, 0, stream>>>(x, xn);
    gemm_k<1,64,64><<<dim3(16,16), 256, 0, stream>>>(xn, Wqt, 1024, 1024, Qb, nullptr, nullptr, 0.125f);

    // attention
    logits_k<<<dim3(8, 8, 32), 256, 0, stream>>>(Qb, Kb, qs, abias, lg);
    softmax_k<<<4096, 256, 0, stream>>>(lg, wsm);
    pv_k<<<dim3(8, 32), 256, 0, stream>>>(wsm, Vt, aout);

    // output projection + residual (x updated in place)
    gemm_k<2,64,64><<<dim3(16,16), 256, 0, stream>>>(aout, Wot, 1024, 1024, x, nullptr, x, 1.0f);

    // FFN
    layernorm_k<0><<<1024, 256, 0, stream>>>(x, xn);
    gemm_k<3,128,128><<<dim3(32, 8), 256, 0, stream>>>(xn, Wf1t, 1024, 4096, ffh, bf1 + (size_t)i*4096, nullptr, 1.0f);
    gemm_k<4,64,64><<<dim3(16,16), 256, 0, stream>>>(ffh, Wf2t, 4096, 1024, x, bf2 + (size_t)i*1024, x, 1.0f);
  }

  layernorm_k<1><<<1024, 256, 0, stream>>>(x, dout);
}

// Round 2
// 549.066 us; speedup vs baseline: 1.4761x; 1.4761x over previous
//
#include <hip/hip_runtime.h>

typedef unsigned short u16;
typedef __attribute__((ext_vector_type(8))) unsigned short u16x8;
typedef __attribute__((ext_vector_type(4))) unsigned short u16x4;
typedef __attribute__((ext_vector_type(4))) float f32x4;

#define DEVI __device__ __forceinline__

// ---------------- helpers ----------------
DEVI u16 f2bf(float f){
  unsigned u = __float_as_uint(f);
  u += 0x7FFFu + ((u >> 16) & 1u);      // round-to-nearest-even
  return (u16)(u >> 16);
}

DEVI void gload16(const void* g, void* l){
  __builtin_amdgcn_global_load_lds((const __attribute__((address_space(1))) void*)g,
                                   (__attribute__((address_space(3))) void*)l, 16, 0, 0);
}

DEVI float wave_sum(float v){
#pragma unroll
  for (int o = 32; o; o >>= 1) v += __shfl_xor(v, o, 64);
  return v;
}

#define MFMA16(a,b,c) __builtin_amdgcn_mfma_f32_16x16x32_bf16((a),(b),(c),0,0,0)

// ---------------- elementwise convert f32 -> bf16 ----------------
__global__ __launch_bounds__(256) void f32_to_bf16_k(const float* __restrict__ in,
                                                     u16* __restrict__ out, int n4){
  int i = blockIdx.x * 256 + threadIdx.x;
  if (i < n4){
    float4 v = ((const float4*)in)[i];
    u16x4 o = { f2bf(v.x), f2bf(v.y), f2bf(v.z), f2bf(v.w) };
    ((u16x4*)out)[i] = o;
  }
}

// ---------------- transpose f32 [R][C] -> bf16 [C][R], z-batched ----------------
__global__ __launch_bounds__(256) void trans_f32_bf16_k(const float* __restrict__ in0,
                                                        u16* __restrict__ out0, int R, int C){
  __shared__ u16 tile[32][33];
  const float* in = in0 + (size_t)blockIdx.z * R * C;
  u16* out = out0 + (size_t)blockIdx.z * R * C;
  const int c0 = blockIdx.x * 32, r0 = blockIdx.y * 32;
  const int tx = threadIdx.x & 31, ty = threadIdx.x >> 5;
#pragma unroll
  for (int k = 0; k < 4; k++)
    tile[ty + k*8][tx] = f2bf(in[(size_t)(r0 + ty + k*8) * C + c0 + tx]);
  __syncthreads();
#pragma unroll
  for (int k = 0; k < 4; k++)
    out[(size_t)(c0 + ty + k*8) * R + r0 + tx] = tile[tx][ty + k*8];
}

// ---------------- V transpose: bf16 [B*T][N*H] -> [B][N][H][T] ----------------
__global__ __launch_bounds__(256) void vtrans_k(const u16* __restrict__ V, u16* __restrict__ Vt){
  __shared__ u16 tile[32][33];
  const int t0 = blockIdx.x * 32;
  const int h0 = blockIdx.y * 32;
  const int bn = blockIdx.z; const int b = bn >> 4, n = bn & 15;
  const int tx = threadIdx.x & 31, ty = threadIdx.x >> 5;
#pragma unroll
  for (int k = 0; k < 4; k++)
    tile[ty + k*8][tx] = V[(size_t)(b*512 + t0 + ty + k*8) * 1024 + n*64 + h0 + tx];
  __syncthreads();
#pragma unroll
  for (int k = 0; k < 4; k++)
    Vt[(size_t)((b*16 + n)*64 + h0 + ty + k*8) * 512 + t0 + tx] = tile[tx][ty + k*8];
}

// ---------------- layernorm: rows of 1024, (x-m)/(std+eps) ----------------
template<int OUTF32>
__global__ __launch_bounds__(256) void layernorm_k(const float* __restrict__ in, void* __restrict__ outp){
  const int row = blockIdx.x;
  const int tid = threadIdx.x;
  const float4 v = ((const float4*)(in + (size_t)row * 1024))[tid];
  __shared__ float sb[8];
  const int wid = tid >> 6, lane = tid & 63;
  float s = wave_sum(v.x + v.y + v.z + v.w);
  if (lane == 0) sb[wid] = s;
  __syncthreads();
  const float mean = (sb[0] + sb[1] + sb[2] + sb[3]) * (1.0f / 1024.0f);
  const float dx = v.x - mean, dy = v.y - mean, dz = v.z - mean, dw = v.w - mean;
  float q = wave_sum(dx*dx + dy*dy + dz*dz + dw*dw);
  if (lane == 0) sb[4 + wid] = q;
  __syncthreads();
  const float sd = sqrtf((sb[4] + sb[5] + sb[6] + sb[7]) * (1.0f / 1024.0f));
  const float inv = 1.0f / (sd + 1e-6f);
  if (OUTF32){
    ((float4*)outp)[(size_t)row * 256 + tid] = make_float4(dx*inv, dy*inv, dz*inv, dw*inv);
  } else {
    u16x4 o = { f2bf(dx*inv), f2bf(dy*inv), f2bf(dz*inv), f2bf(dw*inv) };
    ((u16x4*)outp)[(size_t)row * 256 + tid] = o;
  }
}

// ---------------- time-bias MLP: qs[b,f,t] ----------------
__global__ __launch_bounds__(256) void qsbias_k(const float* __restrict__ dist,
    const float* __restrict__ Wth, const float* __restrict__ bth,
    const float* __restrict__ Wto, const float* __restrict__ bto,
    float* __restrict__ qs){
  const int idx = blockIdx.x * 256 + threadIdx.x;        // over B*F*T/4
  float4 s4 = ((const float4*)dist)[idx];
  float sv[4] = { s4.x, s4.y, s4.z, s4.w };
  float r[4];
  const float b0 = bto[0];
#pragma unroll
  for (int c = 0; c < 4; c++) r[c] = b0;
#pragma unroll
  for (int k = 0; k < 32; k++){
    const float wk = Wth[k], bk = bth[k], ok = Wto[k];
#pragma unroll
    for (int c = 0; c < 4; c++){
      float h = fmaxf(sv[c] * wk + bk, 0.0f);
      r[c] += h * ok;
    }
  }
  ((float4*)qs)[idx] = make_float4(r[0], r[1], r[2], r[3]);
}

// ---------------- GEMM core: C[M][Nd] = A[M][Kd] @ Bt[Nd][Kd]^T, 64x64 tile ---
// T2 swizzle: LDS[row][slot] holds global chunk slot^(row&7); gload_lds dest is
// linear (rule 21), so the SOURCE chunk is pre-swizzled and reads XOR back.
// MODE 0: bf16 out   1: bf16 out * scale   2: f32 out + resid
// MODE 3: bf16 relu(out + bias)            4: f32 out + bias + resid
template<int MODE>
DEVI void gemm_core(const u16* A, const u16* Bt, const int Kd, const int Nd,
                    void* Cout, const float* bias, const float* resid,
                    const float scale, u16* Als, u16* Bls){
  const int tid = threadIdx.x;
  const int wid = tid >> 6, lane = tid & 63;
  const int wm = wid >> 1, wn = wid & 1;
  const int row0 = blockIdx.y * 64, col0 = blockIdx.x * 64;
  const int lrow = lane & 15, g = lane >> 4, e7 = lane & 7;
  f32x4 acc[2][2] = {};

  const int scol = ((lane & 7) ^ ((lane >> 3) & 7)) * 8;    // inverse-swizzled source chunk
  const u16* Ag = A + (size_t)(row0 + wid*16 + (lane >> 3)) * Kd + scol;
  const u16* Bg = Bt + (size_t)(col0 + wid*16 + (lane >> 3)) * Kd + scol;
  u16* AlsW = Als + wid * 16 * 64;
  u16* BlsW = Bls + wid * 16 * 64;

  const int sl0 = ((0*4 + g) ^ e7) * 8;    // swizzled read slots (elements)
  const int sl1 = ((1*4 + g) ^ e7) * 8;

  for (int k0 = 0; k0 < Kd; k0 += 64){
    gload16(Ag + k0, AlsW);
    gload16(Ag + (size_t)8*Kd + k0, AlsW + 8*64);
    gload16(Bg + k0, BlsW);
    gload16(Bg + (size_t)8*Kd + k0, BlsW + 8*64);
    __syncthreads();
#pragma unroll
    for (int ks = 0; ks < 2; ks++){
      const int sl = ks ? sl1 : sl0;
      u16x8 av[2], bv[2];
#pragma unroll
      for (int mi = 0; mi < 2; mi++)
        av[mi] = *(const u16x8*)(Als + (wm*32 + mi*16 + lrow) * 64 + sl);
#pragma unroll
      for (int ni = 0; ni < 2; ni++)
        bv[ni] = *(const u16x8*)(Bls + (wn*32 + ni*16 + lrow) * 64 + sl);
#pragma unroll
      for (int mi = 0; mi < 2; mi++)
#pragma unroll
        for (int ni = 0; ni < 2; ni++)
          acc[mi][ni] = MFMA16(av[mi], bv[ni], acc[mi][ni]);
    }
    __syncthreads();
  }

#pragma unroll
  for (int mi = 0; mi < 2; mi++){
#pragma unroll
    for (int ni = 0; ni < 2; ni++){
      const int col = col0 + wn*32 + ni*16 + lrow;
#pragma unroll
      for (int j = 0; j < 4; j++){
        const int row = row0 + wm*32 + mi*16 + g*4 + j;
        float v = acc[mi][ni][j];
        if (MODE == 1) v *= scale;
        if (MODE == 3) v = fmaxf(v + bias[col], 0.0f);
        if (MODE == 4) v = v + bias[col] + resid[(size_t)row * Nd + col];
        if (MODE == 2) v = v + resid[(size_t)row * Nd + col];
        if (MODE == 0 || MODE == 1 || MODE == 3)
          ((u16*)Cout)[(size_t)row * Nd + col] = f2bf(v);
        else
          ((float*)Cout)[(size_t)row * Nd + col] = v;
      }
    }
  }
}

template<int MODE>
__global__ __launch_bounds__(256) void gemm_k(const u16* __restrict__ A, const u16* __restrict__ Bt,
    const int Kd, const int Nd, void* __restrict__ Cout,
    const float* __restrict__ bias, const float* __restrict__ resid, const float scale){
  __shared__ __align__(16) u16 Als[64*64];
  __shared__ __align__(16) u16 Bls[64*64];
  gemm_core<MODE>(A, Bt, Kd, Nd, Cout, bias, resid, scale, Als, Bls);
}

// K,V,Q projections in one dispatch (z selects), 768 blocks
__global__ __launch_bounds__(256) void gemm3_k(
    const u16* __restrict__ encb, const u16* __restrict__ Wkt, u16* __restrict__ Kb,
    const u16* __restrict__ Wvt, u16* __restrict__ Vb,
    const u16* __restrict__ xn, const u16* __restrict__ Wqt, u16* __restrict__ Qb){
  __shared__ __align__(16) u16 Als[64*64];
  __shared__ __align__(16) u16 Bls[64*64];
  const int z = blockIdx.z;
  if (z == 0)      gemm_core<0>(encb, Wkt, 1024, 1024, Kb, nullptr, nullptr, 1.0f,  Als, Bls);
  else if (z == 1) gemm_core<0>(encb, Wvt, 1024, 1024, Vb, nullptr, nullptr, 1.0f,  Als, Bls);
  else             gemm_core<1>(xn,   Wqt, 1024, 1024, Qb, nullptr, nullptr, 0.125f, Als, Bls);
}

// ---------------- fused flash attention ----------------
// grid (n=16, ftile=8, b=2); 4 waves, wave w owns 16 q-rows.
// S^T = mfma(K, Q^T): lane holds S[fw+l15][t]; softmax row is lane-local in l15.
// P -> per-wave LDS (swizzled), PV = mfma(P, V^T) with V^T frags from L2.
__global__ __launch_bounds__(256, 1) void attn_k(const u16* __restrict__ Q,
    const u16* __restrict__ Kb, const u16* __restrict__ Vt,
    const float* __restrict__ qs, const float* __restrict__ abias,
    u16* __restrict__ aout){
  const int n = blockIdx.x, f0 = blockIdx.y * 64, b = blockIdx.z;
  const int w = threadIdx.x >> 6, lane = threadIdx.x & 63;
  const int l15 = lane & 15, g = lane >> 4, e7 = lane & 7;
  const int fw = f0 + w * 16;
  __shared__ __align__(16) u16 Pl[4][16 * 512];   // 64 KB, per-wave private
  u16* pw = &Pl[w][0];

  // Q fragments (B-operand): lane holds Q[fw+l15][k]
  const u16* qp = Q + ((size_t)b*512 + fw + l15) * 1024 + n*64 + g*8;
  const u16x8 qf0 = *(const u16x8*)qp;
  const u16x8 qf1 = *(const u16x8*)(qp + 32);

  // QK^T: acc[tf] holds S[fw+l15][tf*16 + g*4 + j]
  f32x4 acc[32];
  const u16* kp = Kb + ((size_t)b*512 + l15) * 1024 + n*64 + g*8;
#pragma unroll
  for (int tf = 0; tf < 32; tf++){
    u16x8 k0 = *(const u16x8*)(kp + (size_t)tf*16*1024);
    u16x8 k1 = *(const u16x8*)(kp + (size_t)tf*16*1024 + 32);
    f32x4 z = {0.f, 0.f, 0.f, 0.f};
    z = MFMA16(k0, qf0, z);
    acc[tf] = MFMA16(k1, qf1, z);
  }

  // + qs bias + attn bias, row max
  const float* qsp = qs + ((size_t)b*512 + fw + l15) * 512 + g*4;
  const float* abp = abias + (size_t)b*512 + g*4;
  float m = -3.0e38f;
#pragma unroll
  for (int tf = 0; tf < 32; tf++){
    float4 qv = *(const float4*)(qsp + tf*16);
    float4 av = *(const float4*)(abp + tf*16);
    acc[tf][0] += qv.x + av.x;
    acc[tf][1] += qv.y + av.y;
    acc[tf][2] += qv.z + av.z;
    acc[tf][3] += qv.w + av.w;
    m = fmaxf(m, fmaxf(fmaxf(acc[tf][0], acc[tf][1]), fmaxf(acc[tf][2], acc[tf][3])));
  }
  m = fmaxf(m, __shfl_xor(m, 16, 64));
  m = fmaxf(m, __shfl_xor(m, 32, 64));

  float s = 0.f;
#pragma unroll
  for (int tf = 0; tf < 32; tf++){
#pragma unroll
    for (int j = 0; j < 4; j++){
      float e = __expf(acc[tf][j] - m);
      acc[tf][j] = e; s += e;
    }
  }
  s += __shfl_xor(s, 16, 64);
  s += __shfl_xor(s, 32, 64);
  const float inv = 1.0f / s;
  float invj[4];
#pragma unroll
  for (int j = 0; j < 4; j++) invj[j] = __shfl(inv, g*4 + j, 64);  // inv for row g*4+j

  // store unnormalized P (<=1) row-major [16][512] bf16, chunk-swizzled
#pragma unroll
  for (int tf = 0; tf < 32; tf++){
    const int chunk = tf*2 + (g >> 1);
    const int boff = (l15 << 10) + ((chunk ^ e7) << 4) + ((g & 1) << 3);
    u16x4 pk = { f2bf(acc[tf][0]), f2bf(acc[tf][1]), f2bf(acc[tf][2]), f2bf(acc[tf][3]) };
    *(u16x4*)((char*)pw + boff) = pk;
  }

  // PV: O[f][h] = P[f][:] @ V[:][h];  V^T frags direct from global (L2-resident)
  f32x4 oacc[4] = {};
  const u16* vp = Vt + ((size_t)(b*16 + n)*64 + l15) * 512 + g*8;
  for (int kk = 0; kk < 16; kk++){
    u16x8 pa = *(const u16x8*)((char*)pw + (l15 << 10) + ((((kk << 2) + g) ^ e7) << 4));
#pragma unroll
    for (int nf = 0; nf < 4; nf++){
      u16x8 vb = *(const u16x8*)(vp + (size_t)nf*16*512 + kk*32);
      oacc[nf] = MFMA16(pa, vb, oacc[nf]);
    }
  }

  u16* op = aout + ((size_t)b*512 + fw + g*4) * 1024 + n*64 + l15;
#pragma unroll
  for (int nf = 0; nf < 4; nf++)
#pragma unroll
    for (int j = 0; j < 4; j++)
      op[(size_t)j*1024 + nf*16] = f2bf(oacc[nf][j] * invj[j]);
}

// ---------------- host ----------------
extern "C" void kernel_launch(void* const* d_in, const int* in_sizes, int n_in,
                              void* d_out, int out_size, void* d_ws, size_t ws_size,
                              hipStream_t stream){
  const float* dec_in   = (const float*)d_in[0];
  const float* enc      = (const float*)d_in[1];
  const float* dist     = (const float*)d_in[3];
  const float* abias    = (const float*)d_in[5];
  const float* Wq  = (const float*)d_in[6];
  const float* Wk  = (const float*)d_in[7];
  const float* Wv  = (const float*)d_in[8];
  const float* Wo  = (const float*)d_in[9];
  const float* Wth = (const float*)d_in[10];
  const float* bth = (const float*)d_in[11];
  const float* Wto = (const float*)d_in[12];
  const float* bto = (const float*)d_in[13];
  const float* Wf1 = (const float*)d_in[14];
  const float* bf1 = (const float*)d_in[15];
  const float* Wf2 = (const float*)d_in[16];
  const float* bf2 = (const float*)d_in[17];
  float* dout = (float*)d_out;

  char* wp = (char*)d_ws;
  auto alloc = [&](size_t n) -> char* {
    char* p = wp; wp += (n + 255) & ~(size_t)255; return p;
  };
  float* x     = (float*)alloc((size_t)1048576 * 4);
  u16*  xn     = (u16*)alloc((size_t)1048576 * 2);
  u16*  encb   = (u16*)alloc((size_t)1048576 * 2);
  u16*  Wqt    = (u16*)alloc((size_t)4194304 * 2);   // 4 layers
  u16*  Wkt    = (u16*)alloc((size_t)4194304 * 2);
  u16*  Wvt    = (u16*)alloc((size_t)4194304 * 2);
  u16*  Wot    = (u16*)alloc((size_t)4194304 * 2);
  u16*  Wf1t   = (u16*)alloc((size_t)4194304 * 2);   // per-layer reuse
  u16*  Wf2t   = (u16*)alloc((size_t)4194304 * 2);
  u16*  Kb     = (u16*)alloc((size_t)1048576 * 2);
  u16*  Vb     = (u16*)alloc((size_t)1048576 * 2);
  u16*  Vt     = (u16*)alloc((size_t)1048576 * 2);
  u16*  Qb     = (u16*)alloc((size_t)1048576 * 2);
  float* qs    = (float*)alloc((size_t)524288 * 4);
  u16*  aout   = (u16*)alloc((size_t)1048576 * 2);
  u16*  ffh    = (u16*)alloc((size_t)4194304 * 2);

  hipMemcpyAsync(x, dec_in, (size_t)1048576 * 4, hipMemcpyDeviceToDevice, stream);
  f32_to_bf16_k<<<1024, 256, 0, stream>>>(enc, encb, 262144);

  // all QKVO weight transposes upfront, z-batched over layers
  trans_f32_bf16_k<<<dim3(32, 32, 4), 256, 0, stream>>>(Wq, Wqt, 1024, 1024);
  trans_f32_bf16_k<<<dim3(32, 32, 4), 256, 0, stream>>>(Wk, Wkt, 1024, 1024);
  trans_f32_bf16_k<<<dim3(32, 32, 4), 256, 0, stream>>>(Wv, Wvt, 1024, 1024);
  trans_f32_bf16_k<<<dim3(32, 32, 4), 256, 0, stream>>>(Wo, Wot, 1024, 1024);

  for (int i = 0; i < 4; i++){
    const size_t wo = (size_t)i * 1048576;
    trans_f32_bf16_k<<<dim3(128, 32), 256, 0, stream>>>(Wf1 + (size_t)i*4194304, Wf1t, 1024, 4096);
    trans_f32_bf16_k<<<dim3(32, 128), 256, 0, stream>>>(Wf2 + (size_t)i*4194304, Wf2t, 4096, 1024);

    qsbias_k<<<512, 256, 0, stream>>>(dist, Wth + i*32, bth + i*32, Wto + i*32, bto + i, qs);

    // pre-norm, then K/V/Q projections batched (768 blocks)
    layernorm_k<0><<<1024, 256, 0, stream>>>(x, xn);
    gemm3_k<<<dim3(16, 16, 3), 256, 0, stream>>>(encb, Wkt + wo, Kb, Wvt + wo, Vb, xn, Wqt + wo, Qb);
    vtrans_k<<<dim3(16, 2, 32), 256, 0, stream>>>(Vb, Vt);

    // fused attention (logits + biases + softmax + PV)
    attn_k<<<dim3(16, 8, 2), 256, 0, stream>>>(Qb, Kb, Vt, qs, abias, aout);

    // output projection + residual (x updated in place)
    gemm_k<2><<<dim3(16, 16), 256, 0, stream>>>(aout, Wot + wo, 1024, 1024, x, nullptr, x, 1.0f);

    // FFN
    layernorm_k<0><<<1024, 256, 0, stream>>>(x, xn);
    gemm_k<3><<<dim3(64, 16), 256, 0, stream>>>(xn, Wf1t, 1024, 4096, ffh, bf1 + (size_t)i*4096, nullptr, 1.0f);
    gemm_k<4><<<dim3(16, 16), 256, 0, stream>>>(ffh, Wf2t, 4096, 1024, x, bf2 + (size_t)i*1024, x, 1.0f);
  }

  layernorm_k<1><<<1024, 256, 0, stream>>>(x, dout);
}